// Round 4
// baseline (1074.832 us; speedup 1.0000x reference)
//
#include <hip/hip_runtime.h>

// Kalman filter, B=8192 batches, M=4, N=8, T=512.
// Covariance/gain recursion is data-independent -> compute once (kernel 1),
// all 512 steps exactly (near-unit-root F: gain freeze at t=96 gave 0.56
// absmax). MUST use the Joseph-stabilized update like the reference: the
// simple form P-KHP diverges to NaN in fp32 by t~500 (measured round 3).
// Mean recursion per batch: out_t = G mu, mu' = F mu + K_t (x_t - out_t).

#define B_BATCH 8192
#define M_MEAS 4
#define N_ST 8
#define T_STEPS 512

// ---------------- Kernel 1: Riccati / gain recursion (1 block, 1 wave) -----
// 64 lanes = 8x8 grid (i = lane>>3, j = lane&7); element (i,j) per lane.
__global__ __launch_bounds__(64) void kf_cov(
    const float* __restrict__ Fp, const float* __restrict__ Hp,
    const float* __restrict__ Qp, const float* __restrict__ Rp,
    const float* __restrict__ stdp, float* __restrict__ Kws)
{
    const int lane = threadIdx.x;
    const int i = lane >> 3, j = lane & 7;
    __shared__ float Pm[64], T1[64], PP[64], T2[32], Sm[16], SI[16],
                     Wm[32], Am[64], Bm[64], Em[32], Hs[32], Rs[16];

    float Fi[8], Fj[8], Hi[8];
#pragma unroll
    for (int k = 0; k < 8; ++k) {
        Fi[k] = Fp[8 * i + k];
        Fj[k] = Fp[8 * j + k];
        Hi[k] = (i < 4) ? Hp[8 * i + k] : 0.f;
    }
    const float Qij = Qp[lane];
    const float Rij = (i < 4 && j < 4) ? Rp[4 * i + j] : 0.f;
    if (i < 4) Hs[8 * i + j] = Hp[8 * i + j];      // Hs[m][j]
    if (i < 4 && j < 4) Rs[4 * i + j] = Rij;       // Rs[m][o]
    {
        float s0 = stdp[i];
        Pm[lane] = (i == j) ? s0 * s0 : 0.f;  // P0 = diag(std^2), mean0 = 0
    }
    __syncthreads();

    for (int t = 0; t < T_STEPS; ++t) {
        // ---- predict: T1 = F @ P
        float acc = 0.f;
#pragma unroll
        for (int k = 0; k < 8; ++k) acc += Fi[k] * Pm[8 * k + j];
        T1[lane] = acc;
        __syncthreads();
        // Ppred = T1 @ F^T + Q   (P symmetric)
        acc = Qij;
#pragma unroll
        for (int k = 0; k < 8; ++k) acc += T1[8 * i + k] * Fj[k];
        PP[lane] = acc;
        __syncthreads();
        // T2 = H @ Ppred (4x8)
        if (i < 4) {
            acc = 0.f;
#pragma unroll
            for (int k = 0; k < 8; ++k) acc += Hi[k] * PP[8 * k + j];
            T2[8 * i + j] = acc;
        }
        __syncthreads();
        // S = T2 @ H^T + R (4x4):  S[i][j] = sum_k T2[i][k] H[j][k]
        if (i < 4 && j < 4) {
            acc = Rij;
#pragma unroll
            for (int k = 0; k < 8; ++k) acc += T2[8 * i + k] * Hs[8 * j + k];
            Sm[4 * i + j] = acc;
        }
        __syncthreads();
        // SI = inv(S); S symmetric => adjugate orientation-safe.
        // All lanes compute redundantly; lane 0 writes.
        {
            float A0 = Sm[0], A1 = Sm[1], A2 = Sm[2], A3 = Sm[3];
            float A4 = Sm[4], A5 = Sm[5], A6 = Sm[6], A7 = Sm[7];
            float A8 = Sm[8], A9 = Sm[9], A10 = Sm[10], A11 = Sm[11];
            float A12 = Sm[12], A13 = Sm[13], A14 = Sm[14], A15 = Sm[15];
            float b00 = A0 * A5 - A1 * A4, b01 = A0 * A6 - A2 * A4;
            float b02 = A0 * A7 - A3 * A4, b03 = A1 * A6 - A2 * A5;
            float b04 = A1 * A7 - A3 * A5, b05 = A2 * A7 - A3 * A6;
            float b06 = A8 * A13 - A9 * A12, b07 = A8 * A14 - A10 * A12;
            float b08 = A8 * A15 - A11 * A12, b09 = A9 * A14 - A10 * A13;
            float b10 = A9 * A15 - A11 * A13, b11 = A10 * A15 - A11 * A14;
            float det = b00 * b11 - b01 * b10 + b02 * b09 + b03 * b08 -
                        b04 * b07 + b05 * b06;
            float rd = 1.0f / det;
            if (lane == 0) {
                SI[0]  = ( A5 * b11 - A6 * b10 + A7 * b09) * rd;
                SI[1]  = (-A1 * b11 + A2 * b10 - A3 * b09) * rd;
                SI[2]  = ( A13 * b05 - A14 * b04 + A15 * b03) * rd;
                SI[3]  = (-A9 * b05 + A10 * b04 - A11 * b03) * rd;
                SI[4]  = (-A4 * b11 + A6 * b08 - A7 * b07) * rd;
                SI[5]  = ( A0 * b11 - A2 * b08 + A3 * b07) * rd;
                SI[6]  = (-A12 * b05 + A14 * b02 - A15 * b01) * rd;
                SI[7]  = ( A8 * b05 - A10 * b02 + A11 * b01) * rd;
                SI[8]  = ( A4 * b10 - A5 * b08 + A7 * b06) * rd;
                SI[9]  = (-A0 * b10 + A1 * b08 - A3 * b06) * rd;
                SI[10] = ( A12 * b04 - A13 * b02 + A15 * b00) * rd;
                SI[11] = (-A8 * b04 + A9 * b02 - A11 * b00) * rd;
                SI[12] = (-A4 * b09 + A5 * b07 - A6 * b06) * rd;
                SI[13] = ( A0 * b09 - A1 * b07 + A2 * b06) * rd;
                SI[14] = (-A12 * b03 + A13 * b01 - A14 * b00) * rd;
                SI[15] = ( A8 * b03 - A9 * b01 + A10 * b00) * rd;
            }
        }
        __syncthreads();
        // W = Sinv @ T2 (4x8).  K = Ppred H^T Sinv = T2^T Sinv = W^T.
        // K[n][m] = Wm[8*m+n].
        if (i < 4) {
            acc = 0.f;
#pragma unroll
            for (int p = 0; p < 4; ++p) acc += SI[4 * i + p] * T2[8 * p + j];
            Wm[8 * i + j] = acc;
            Kws[t * 32 + j * 4 + i] = acc;  // layout: Kws[t][n][m]
        }
        __syncthreads();
        // A = I - K@H  (8x8); E = K@R (8x4)
        acc = (i == j) ? 1.f : 0.f;
#pragma unroll
        for (int m = 0; m < 4; ++m) acc -= Wm[8 * m + i] * Hs[8 * m + j];
        Am[lane] = acc;
        if (j < 4) {
            acc = 0.f;
#pragma unroll
            for (int m = 0; m < 4; ++m) acc += Wm[8 * m + i] * Rs[4 * m + j];
            Em[4 * i + j] = acc;
        }
        __syncthreads();
        // B = A @ Ppred
        acc = 0.f;
#pragma unroll
        for (int k = 0; k < 8; ++k) acc += Am[8 * i + k] * PP[8 * k + j];
        Bm[lane] = acc;
        __syncthreads();
        // P_new = B @ A^T + E @ K^T   (Joseph)
        acc = 0.f;
#pragma unroll
        for (int k = 0; k < 8; ++k) acc += Bm[8 * i + k] * Am[8 * j + k];
#pragma unroll
        for (int o = 0; o < 4; ++o) acc += Em[4 * i + o] * Wm[8 * o + j];
        __syncthreads();
        Pm[lane] = acc;
        __syncthreads();
    }
}

// ---------------- Kernel 2: mean/output recursion, 1 thread per batch ------
__global__ __launch_bounds__(64) void kf_main(
    const float* __restrict__ xp, const float* __restrict__ Fp,
    const float* __restrict__ Hp, const float* __restrict__ Kws,
    float* __restrict__ outp)
{
    const int b = blockIdx.x * 64 + threadIdx.x;

    // F (row-major NxN) and G = H @ F (MxN); uniform -> scalar regs
    float Fv[N_ST][N_ST];
#pragma unroll
    for (int n = 0; n < N_ST; ++n)
#pragma unroll
        for (int k = 0; k < N_ST; ++k) Fv[n][k] = Fp[8 * n + k];

    float G[M_MEAS][N_ST];
#pragma unroll
    for (int m = 0; m < M_MEAS; ++m) {
#pragma unroll
        for (int n = 0; n < N_ST; ++n) {
            float acc = 0.f;
#pragma unroll
            for (int k = 0; k < N_ST; ++k) acc += Hp[8 * m + k] * Fv[k][n];
            G[m][n] = acc;
        }
    }

    float mu[N_ST];
#pragma unroll
    for (int n = 0; n < N_ST; ++n) mu[n] = 0.f;

    const float* xb = xp + (size_t)b * (M_MEAS * T_STEPS);
    float* ob = outp + (size_t)b * (M_MEAS * T_STEPS);

    for (int t4 = 0; t4 < T_STEPS / 4; ++t4) {
        float4 xq[M_MEAS];
#pragma unroll
        for (int m = 0; m < M_MEAS; ++m)
            xq[m] = *(const float4*)(xb + m * T_STEPS + t4 * 4);

        float obuf[M_MEAS][4];

#pragma unroll
        for (int s = 0; s < 4; ++s) {
            const int t = t4 * 4 + s;
            const float4* kq = (const float4*)(Kws + t * 32);
            float4 kv[N_ST];
#pragma unroll
            for (int n = 0; n < N_ST; ++n) kv[n] = kq[n];

            // out = G mu ; resid = x - out
            float resid[M_MEAS];
#pragma unroll
            for (int m = 0; m < M_MEAS; ++m) {
                float acc = 0.f;
#pragma unroll
                for (int n = 0; n < N_ST; ++n) acc += G[m][n] * mu[n];
                obuf[m][s] = acc;
                const float xv = (s == 0) ? xq[m].x
                               : (s == 1) ? xq[m].y
                               : (s == 2) ? xq[m].z : xq[m].w;
                resid[m] = xv - acc;
            }
            // mu' = F mu + K resid
            float nmu[N_ST];
#pragma unroll
            for (int n = 0; n < N_ST; ++n) {
                float acc = 0.f;
#pragma unroll
                for (int k = 0; k < N_ST; ++k) acc += Fv[n][k] * mu[k];
                acc += kv[n].x * resid[0] + kv[n].y * resid[1] +
                       kv[n].z * resid[2] + kv[n].w * resid[3];
                nmu[n] = acc;
            }
#pragma unroll
            for (int n = 0; n < N_ST; ++n) mu[n] = nmu[n];
        }

#pragma unroll
        for (int m = 0; m < M_MEAS; ++m) {
            *(float4*)(ob + m * T_STEPS + t4 * 4) =
                make_float4(obuf[m][0], obuf[m][1], obuf[m][2], obuf[m][3]);
        }
    }
}

extern "C" void kernel_launch(void* const* d_in, const int* in_sizes, int n_in,
                              void* d_out, int out_size, void* d_ws, size_t ws_size,
                              hipStream_t stream) {
    const float* x   = (const float*)d_in[0];
    const float* F   = (const float*)d_in[1];
    const float* H   = (const float*)d_in[2];
    const float* Q   = (const float*)d_in[3];
    const float* R   = (const float*)d_in[4];
    const float* std0 = (const float*)d_in[5];
    float* out = (float*)d_out;
    float* Kws = (float*)d_ws;  // T_STEPS*32 floats = 64 KB

    kf_cov<<<dim3(1), dim3(64), 0, stream>>>(F, H, Q, R, std0, Kws);
    kf_main<<<dim3(B_BATCH / 64), dim3(64), 0, stream>>>(x, F, H, Kws, out);
}